// Round 1
// baseline (1102.285 us; speedup 1.0000x reference)
//
#include <hip/hip_runtime.h>

#define N_NODES 50000
#define N_EDGES 800000
#define IN_F 128
#define HID 128
#define N_CLS 40

static inline int cdiv(int a, int b) { return (a + b - 1) / b; }

// deg[col[e]] += ew[e]  (deg buffer pre-zeroed; self-loop +1 added in dinv pass)
__global__ void deg_kernel(const int* __restrict__ col, const float* __restrict__ ew,
                           float* __restrict__ deg) {
    int e = blockIdx.x * blockDim.x + threadIdx.x;
    if (e < N_EDGES) atomicAdd(&deg[col[e]], ew[e]);
}

// in-place: deg -> rsqrt(deg + 1)
__global__ void dinv_kernel(float* __restrict__ deg_dinv) {
    int i = blockIdx.x * blockDim.x + threadIdx.x;
    if (i < N_NODES) {
        float d = deg_dinv[i] + 1.0f;   // self-loop weight 1; d > 0 always
        deg_dinv[i] = rsqrtf(d);
    }
}

__global__ void norm_kernel(const int* __restrict__ row, const int* __restrict__ col,
                            const float* __restrict__ ew, const float* __restrict__ dinv,
                            float* __restrict__ norm) {
    int e = blockIdx.x * blockDim.x + threadIdx.x;
    if (e < N_EDGES) norm[e] = dinv[row[e]] * ew[e] * dinv[col[e]];
}

// h = X @ W, X:[N,128], W:[128,128]. Block=256 handles 16 rows.
// Thread t: col c = t&127, row-group r0 = t>>7; 8 rows (r0, r0+2, ..., r0+14).
// W load amortized 8x; xs reads are LDS broadcasts.
__global__ void gemm128_kernel(const float* __restrict__ X, const float* __restrict__ W,
                               float* __restrict__ out) {
    __shared__ float xs[16 * IN_F];
    const int row0 = blockIdx.x * 16;
    for (int i = threadIdx.x; i < 16 * IN_F; i += 256)
        xs[i] = X[(size_t)row0 * IN_F + i];
    __syncthreads();
    const int c = threadIdx.x & 127;
    const int r0 = threadIdx.x >> 7;
    float acc[8] = {0.f, 0.f, 0.f, 0.f, 0.f, 0.f, 0.f, 0.f};
    #pragma unroll 4
    for (int k = 0; k < IN_F; ++k) {
        float w = W[k * 128 + c];
        #pragma unroll
        for (int j = 0; j < 8; ++j)
            acc[j] = fmaf(xs[(r0 + 2 * j) * IN_F + k], w, acc[j]);
    }
    #pragma unroll
    for (int j = 0; j < 8; ++j)
        out[(size_t)(row0 + r0 + 2 * j) * 128 + c] = acc[j];
}

// h = X @ W, X:[N,128], W:[128,40]. Block=256 handles 16 rows (640 outputs).
__global__ void gemm40_kernel(const float* __restrict__ X, const float* __restrict__ W,
                              float* __restrict__ out) {
    __shared__ float xs[16 * IN_F];
    const int row0 = blockIdx.x * 16;
    for (int i = threadIdx.x; i < 16 * IN_F; i += 256)
        xs[i] = X[(size_t)row0 * IN_F + i];
    __syncthreads();
    for (int idx = threadIdx.x; idx < 16 * N_CLS; idx += 256) {
        int r = idx / N_CLS;
        int c = idx % N_CLS;
        float acc = 0.f;
        #pragma unroll 8
        for (int k = 0; k < IN_F; ++k)
            acc = fmaf(xs[r * IN_F + k], W[k * N_CLS + c], acc);
        out[(size_t)(row0 + r) * N_CLS + c] = acc;
    }
}

// agg[col[e]*F + f] += norm[e] * h[row[e]*F + f], 32 lanes per edge
template <int F>
__global__ void scatter_kernel(const int* __restrict__ row, const int* __restrict__ col,
                               const float* __restrict__ norm, const float* __restrict__ h,
                               float* __restrict__ agg) {
    int t = blockIdx.x * blockDim.x + threadIdx.x;
    int e = t >> 5;
    int lane = t & 31;
    if (e >= N_EDGES) return;
    int r = row[e];
    int c = col[e];
    float nv = norm[e];
    const float* hr = h + (size_t)r * F;
    float* ac = agg + (size_t)c * F;
    #pragma unroll
    for (int f = lane; f < F; f += 32)
        atomicAdd(&ac[f], nv * hr[f]);
}

// out = agg + dinv^2 * h + b  (+ relu)
template <int F, bool RELU>
__global__ void epilogue_kernel(const float* __restrict__ agg_in, const float* __restrict__ h,
                                const float* __restrict__ dinv, const float* __restrict__ b,
                                float* __restrict__ out) {
    int idx = blockIdx.x * blockDim.x + threadIdx.x;
    if (idx >= N_NODES * F) return;
    int i = idx / F;
    int f = idx % F;
    float di = dinv[i];
    float v = agg_in[idx] + di * di * h[idx] + b[f];
    if (RELU) v = fmaxf(v, 0.f);
    out[idx] = v;
}

extern "C" void kernel_launch(void* const* d_in, const int* in_sizes, int n_in,
                              void* d_out, int out_size, void* d_ws, size_t ws_size,
                              hipStream_t stream) {
    const float* x  = (const float*)d_in[0];
    const float* ew = (const float*)d_in[1];
    const float* W1 = (const float*)d_in[2];
    const float* b1 = (const float*)d_in[3];
    const float* W2 = (const float*)d_in[4];
    const float* b2 = (const float*)d_in[5];
    const float* W3 = (const float*)d_in[6];
    const float* b3 = (const float*)d_in[7];
    const int*   ei = (const int*)d_in[8];
    const int* row = ei;
    const int* col = ei + N_EDGES;
    float* out = (float*)d_out;

    char* ws = (char*)d_ws;
    size_t off = 0;
    auto alloc = [&](size_t bytes) -> float* {
        float* p = (float*)(ws + off);
        off = (off + bytes + 255) & ~(size_t)255;
        return p;
    };
    float* dinv = alloc((size_t)N_NODES * 4);
    float* norm = alloc((size_t)N_EDGES * 4);
    float* h    = alloc((size_t)N_NODES * HID * 4);
    float* agg  = alloc((size_t)N_NODES * HID * 4);

    // --- normalization (shared across layers) ---
    hipMemsetAsync(dinv, 0, (size_t)N_NODES * 4, stream);
    deg_kernel<<<cdiv(N_EDGES, 256), 256, 0, stream>>>(col, ew, dinv);
    dinv_kernel<<<cdiv(N_NODES, 256), 256, 0, stream>>>(dinv);
    norm_kernel<<<cdiv(N_EDGES, 256), 256, 0, stream>>>(row, col, ew, dinv, norm);

    const int gemm_blocks = N_NODES / 16;           // 3125
    const int scat_blocks = cdiv(N_EDGES * 32, 256); // 100000

    // --- layer 1 ---
    gemm128_kernel<<<gemm_blocks, 256, 0, stream>>>(x, W1, h);
    hipMemsetAsync(agg, 0, (size_t)N_NODES * 128 * 4, stream);
    scatter_kernel<128><<<scat_blocks, 256, 0, stream>>>(row, col, norm, h, agg);
    epilogue_kernel<128, true><<<cdiv(N_NODES * 128, 256), 256, 0, stream>>>(agg, h, dinv, b1, agg);

    // --- layer 2 ---
    gemm128_kernel<<<gemm_blocks, 256, 0, stream>>>(agg, W2, h);
    hipMemsetAsync(agg, 0, (size_t)N_NODES * 128 * 4, stream);  // stream-ordered after gemm
    scatter_kernel<128><<<scat_blocks, 256, 0, stream>>>(row, col, norm, h, agg);
    epilogue_kernel<128, true><<<cdiv(N_NODES * 128, 256), 256, 0, stream>>>(agg, h, dinv, b2, agg);

    // --- layer 3 (output, no relu) ---
    gemm40_kernel<<<gemm_blocks, 256, 0, stream>>>(agg, W3, h);  // h reused as [N,40]
    hipMemsetAsync(out, 0, (size_t)out_size * 4, stream);
    scatter_kernel<40><<<scat_blocks, 256, 0, stream>>>(row, col, norm, h, out);
    epilogue_kernel<40, false><<<cdiv(N_NODES * N_CLS, 256), 256, 0, stream>>>(out, h, dinv, b3, out);
}

// Round 2
// 517.418 us; speedup vs baseline: 2.1304x; 2.1304x over previous
//
#include <hip/hip_runtime.h>

#define N_NODES 50000
#define N_EDGES 800000
#define IN_F 128
#define HID 128
#define N_CLS 40
#define SCAN_BLOCKS 196  // ceil(50000/256)

static inline int cdiv(int a, int b) { return (a + b - 1) / b; }

// counts[c]++ and deg[c] += ew  (both pre-zeroed)
__global__ void count_deg_kernel(const int* __restrict__ col, const float* __restrict__ ew,
                                 int* __restrict__ counts, float* __restrict__ deg) {
    int e = blockIdx.x * blockDim.x + threadIdx.x;
    if (e < N_EDGES) {
        int c = col[e];
        atomicAdd(&counts[c], 1);
        atomicAdd(&deg[c], ew[e]);
    }
}

// in-place: deg -> rsqrt(deg + 1)   (self-loop weight 1)
__global__ void dinv_kernel(float* __restrict__ deg_dinv) {
    int i = blockIdx.x * blockDim.x + threadIdx.x;
    if (i < N_NODES) deg_dinv[i] = rsqrtf(deg_dinv[i] + 1.0f);
}

// ---- two-level exclusive scan of counts[N_NODES] -> row_ptr / cursor ----
__global__ void scan_reduce(const int* __restrict__ counts, int* __restrict__ blockSums) {
    __shared__ int s[256];
    int i = blockIdx.x * 256 + threadIdx.x;
    s[threadIdx.x] = (i < N_NODES) ? counts[i] : 0;
    __syncthreads();
    for (int off = 128; off > 0; off >>= 1) {
        if (threadIdx.x < off) s[threadIdx.x] += s[threadIdx.x + off];
        __syncthreads();
    }
    if (threadIdx.x == 0) blockSums[blockIdx.x] = s[0];
}

__global__ void scan_offsets(const int* __restrict__ blockSums, int* __restrict__ offsets) {
    __shared__ int s[256];
    int t = threadIdx.x;
    int v = (t < SCAN_BLOCKS) ? blockSums[t] : 0;
    s[t] = v;
    __syncthreads();
    for (int off = 1; off < 256; off <<= 1) {
        int tmp = (t >= off) ? s[t - off] : 0;
        __syncthreads();
        s[t] += tmp;
        __syncthreads();
    }
    offsets[t] = s[t] - v;  // exclusive
}

__global__ void scan_final(const int* __restrict__ counts, const int* __restrict__ offsets,
                           int* __restrict__ row_ptr, int* __restrict__ cursor) {
    __shared__ int s[256];
    int t = threadIdx.x;
    int i = blockIdx.x * 256 + t;
    int v = (i < N_NODES) ? counts[i] : 0;
    s[t] = v;
    __syncthreads();
    for (int off = 1; off < 256; off <<= 1) {
        int tmp = (t >= off) ? s[t - off] : 0;
        __syncthreads();
        s[t] += tmp;
        __syncthreads();
    }
    int incl = s[t] + offsets[blockIdx.x];
    if (i < N_NODES) {
        int excl = incl - v;
        row_ptr[i] = excl;
        cursor[i] = excl;
        if (i == N_NODES - 1) row_ptr[N_NODES] = incl;
    }
}

// scatter edges into CSR slots grouped by destination; store (src, norm) packed
__global__ void fill_kernel(const int* __restrict__ row, const int* __restrict__ col,
                            const float* __restrict__ ew, const float* __restrict__ dinv,
                            int* __restrict__ cursor, uint2* __restrict__ csr) {
    int e = blockIdx.x * blockDim.x + threadIdx.x;
    if (e >= N_EDGES) return;
    int r = row[e];
    int c = col[e];
    int pos = atomicAdd(&cursor[c], 1);
    float w = dinv[r] * ew[e] * dinv[c];
    csr[pos] = make_uint2((unsigned)r, __float_as_uint(w));
}

// h = X @ W, X:[N,128], W:[128,128]. Block=256 handles 16 rows.
__global__ void gemm128_kernel(const float* __restrict__ X, const float* __restrict__ W,
                               float* __restrict__ out) {
    __shared__ float xs[16 * IN_F];
    const int row0 = blockIdx.x * 16;
    for (int i = threadIdx.x; i < 16 * IN_F; i += 256)
        xs[i] = X[(size_t)row0 * IN_F + i];
    __syncthreads();
    const int c = threadIdx.x & 127;
    const int r0 = threadIdx.x >> 7;
    float acc[8] = {0.f, 0.f, 0.f, 0.f, 0.f, 0.f, 0.f, 0.f};
    #pragma unroll 4
    for (int k = 0; k < IN_F; ++k) {
        float w = W[k * 128 + c];
        #pragma unroll
        for (int j = 0; j < 8; ++j)
            acc[j] = fmaf(xs[(r0 + 2 * j) * IN_F + k], w, acc[j]);
    }
    #pragma unroll
    for (int j = 0; j < 8; ++j)
        out[(size_t)(row0 + r0 + 2 * j) * 128 + c] = acc[j];
}

// h = X @ W, X:[N,128], W:[128,40].
__global__ void gemm40_kernel(const float* __restrict__ X, const float* __restrict__ W,
                              float* __restrict__ out) {
    __shared__ float xs[16 * IN_F];
    const int row0 = blockIdx.x * 16;
    for (int i = threadIdx.x; i < 16 * IN_F; i += 256)
        xs[i] = X[(size_t)row0 * IN_F + i];
    __syncthreads();
    for (int idx = threadIdx.x; idx < 16 * N_CLS; idx += 256) {
        int r = idx / N_CLS;
        int c = idx % N_CLS;
        float acc = 0.f;
        #pragma unroll 8
        for (int k = 0; k < IN_F; ++k)
            acc = fmaf(xs[r * IN_F + k], W[k * N_CLS + c], acc);
        out[(size_t)(row0 + r) * N_CLS + c] = acc;
    }
}

// Pull-aggregation + fused epilogue, F=128: one wave per node, lane handles float2.
// out[n] = sum_in_edges w*h[src] + dinv[n]^2*h[n] + b   (+relu)
template <bool RELU>
__global__ void agg128_kernel(const int* __restrict__ row_ptr, const uint2* __restrict__ csr,
                              const float* __restrict__ h, const float* __restrict__ dinv,
                              const float* __restrict__ b, float* __restrict__ out) {
    int wave = threadIdx.x >> 6;
    int lane = threadIdx.x & 63;
    int node = blockIdx.x * 4 + wave;
    if (node >= N_NODES) return;
    int beg = row_ptr[node];
    int end = row_ptr[node + 1];
    int f = lane * 2;
    float2 acc = make_float2(0.f, 0.f);
    int k = beg;
    uint2 nxt;
    if (k < end) nxt = csr[k];
    while (k < end) {
        uint2 cur = nxt;
        ++k;
        if (k < end) nxt = csr[k];  // prefetch next edge record
        float w = __uint_as_float(cur.y);
        float2 hv = *(const float2*)&h[(size_t)cur.x * 128 + f];
        acc.x = fmaf(w, hv.x, acc.x);
        acc.y = fmaf(w, hv.y, acc.y);
    }
    float di = dinv[node];
    float di2 = di * di;
    float2 hs = *(const float2*)&h[(size_t)node * 128 + f];
    float2 bb = *(const float2*)&b[f];
    acc.x = fmaf(di2, hs.x, acc.x) + bb.x;
    acc.y = fmaf(di2, hs.y, acc.y) + bb.y;
    if (RELU) {
        acc.x = fmaxf(acc.x, 0.f);
        acc.y = fmaxf(acc.y, 0.f);
    }
    *(float2*)&out[(size_t)node * 128 + f] = acc;
}

// Pull-aggregation + epilogue, F=40: one wave per node, lanes 0..39 active.
__global__ void agg40_kernel(const int* __restrict__ row_ptr, const uint2* __restrict__ csr,
                             const float* __restrict__ h, const float* __restrict__ dinv,
                             const float* __restrict__ b, float* __restrict__ out) {
    int wave = threadIdx.x >> 6;
    int lane = threadIdx.x & 63;
    int node = blockIdx.x * 4 + wave;
    if (node >= N_NODES || lane >= N_CLS) return;
    int beg = row_ptr[node];
    int end = row_ptr[node + 1];
    float acc = 0.f;
    int k = beg;
    uint2 nxt;
    if (k < end) nxt = csr[k];
    while (k < end) {
        uint2 cur = nxt;
        ++k;
        if (k < end) nxt = csr[k];
        float w = __uint_as_float(cur.y);
        acc = fmaf(w, h[(size_t)cur.x * N_CLS + lane], acc);
    }
    float di = dinv[node];
    acc = fmaf(di * di, h[(size_t)node * N_CLS + lane], acc) + b[lane];
    out[(size_t)node * N_CLS + lane] = acc;
}

extern "C" void kernel_launch(void* const* d_in, const int* in_sizes, int n_in,
                              void* d_out, int out_size, void* d_ws, size_t ws_size,
                              hipStream_t stream) {
    const float* x  = (const float*)d_in[0];
    const float* ew = (const float*)d_in[1];
    const float* W1 = (const float*)d_in[2];
    const float* b1 = (const float*)d_in[3];
    const float* W2 = (const float*)d_in[4];
    const float* b2 = (const float*)d_in[5];
    const float* W3 = (const float*)d_in[6];
    const float* b3 = (const float*)d_in[7];
    const int*   ei = (const int*)d_in[8];
    const int* row = ei;
    const int* col = ei + N_EDGES;
    float* out = (float*)d_out;

    char* ws = (char*)d_ws;
    size_t off = 0;
    auto alloc = [&](size_t bytes) -> void* {
        void* p = (void*)(ws + off);
        off = (off + bytes + 255) & ~(size_t)255;
        return p;
    };
    int*   counts    = (int*)alloc((size_t)N_NODES * 4);
    float* deg_dinv  = (float*)alloc((size_t)N_NODES * 4);
    int*   blockSums = (int*)alloc(256 * 4);
    int*   offsets   = (int*)alloc(256 * 4);
    int*   row_ptr   = (int*)alloc((size_t)(N_NODES + 1) * 4);
    int*   cursor    = (int*)alloc((size_t)N_NODES * 4);
    uint2* csr       = (uint2*)alloc((size_t)N_EDGES * 8);
    float* h         = (float*)alloc((size_t)N_NODES * HID * 4);
    float* hagg      = (float*)alloc((size_t)N_NODES * HID * 4);

    // --- CSR build + normalization (shared across layers) ---
    hipMemsetAsync(counts, 0, (size_t)N_NODES * 4, stream);
    hipMemsetAsync(deg_dinv, 0, (size_t)N_NODES * 4, stream);
    count_deg_kernel<<<cdiv(N_EDGES, 256), 256, 0, stream>>>(col, ew, counts, deg_dinv);
    dinv_kernel<<<cdiv(N_NODES, 256), 256, 0, stream>>>(deg_dinv);
    scan_reduce<<<SCAN_BLOCKS, 256, 0, stream>>>(counts, blockSums);
    scan_offsets<<<1, 256, 0, stream>>>(blockSums, offsets);
    scan_final<<<SCAN_BLOCKS, 256, 0, stream>>>(counts, offsets, row_ptr, cursor);
    fill_kernel<<<cdiv(N_EDGES, 256), 256, 0, stream>>>(row, col, ew, deg_dinv, cursor, csr);

    const int gemm_blocks = N_NODES / 16;  // 3125
    const int agg_blocks = cdiv(N_NODES, 4);  // 12500

    // --- layer 1 ---
    gemm128_kernel<<<gemm_blocks, 256, 0, stream>>>(x, W1, h);
    agg128_kernel<true><<<agg_blocks, 256, 0, stream>>>(row_ptr, csr, h, deg_dinv, b1, hagg);

    // --- layer 2 ---
    gemm128_kernel<<<gemm_blocks, 256, 0, stream>>>(hagg, W2, h);
    agg128_kernel<true><<<agg_blocks, 256, 0, stream>>>(row_ptr, csr, h, deg_dinv, b2, hagg);

    // --- layer 3 (output, no relu) ---
    gemm40_kernel<<<gemm_blocks, 256, 0, stream>>>(hagg, W3, h);  // h reused as [N,40]
    agg40_kernel<<<agg_blocks, 256, 0, stream>>>(row_ptr, csr, h, deg_dinv, b3, out);
}

// Round 3
// 454.283 us; speedup vs baseline: 2.4264x; 1.1390x over previous
//
#include <hip/hip_runtime.h>

#define N_NODES 50000
#define N_EDGES 800000
#define IN_F 128
#define HID 128
#define N_CLS 40
#define SCAN_BLOCKS 196        // ceil(50000/256)
#define GEMM_TILE_ROWS 32
#define GEMM_BLOCKS 1563       // ceil(50000/32)
#define CNT_BLOCKS 3125        // ceil(800000/256)
#define DEG_SCALE 2097152.0f   // 2^21 fixed-point for ew
#define DEG_MASK ((1ull << 44) - 1)

static inline int cdiv(int a, int b) { return (a + b - 1) / b; }

// ---- packed count+deg: one 64-bit atomic per edge ----
// packed[c] accumulates (1<<44) | round(ew * 2^21). counts fit above bit 44
// (max 800k < 2^20); deg sum fits below (max 800k*2^21 < 2^44).
__device__ __forceinline__ void count_deg_body(int e, const int* __restrict__ col,
                                               const float* __restrict__ ew,
                                               unsigned long long* __restrict__ packed) {
    if (e < N_EDGES) {
        int c = col[e];
        unsigned long long v =
            (1ull << 44) | (unsigned long long)__float2uint_rn(ew[e] * DEG_SCALE);
        atomicAdd(&packed[c], v);
    }
}

// ---- gemm128 body: 32 rows x 128 cols per block, 4x4 register tile ----
__device__ __forceinline__ void gemm128_body(int b, const float* __restrict__ X,
                                             const float* __restrict__ W,
                                             float* __restrict__ out) {
    __shared__ float xsT[IN_F][GEMM_TILE_ROWS + 4];  // k-major, pad 4 keeps 16B align
    __shared__ float wch[32][128];
    const int t = threadIdx.x;
    const int row0 = b * GEMM_TILE_ROWS;

    // stage X tile transposed: 32 rows x 128 k -> xsT[k][row]
    #pragma unroll
    for (int i = 0; i < 4; ++i) {
        int idx = t + i * 256;          // [0,1024)
        int row = idx >> 5;             // 0..31
        int k4  = idx & 31;             // float4 index along k
        float4 v = make_float4(0.f, 0.f, 0.f, 0.f);
        if (row0 + row < N_NODES)
            v = *(const float4*)&X[(size_t)(row0 + row) * IN_F + k4 * 4];
        xsT[k4 * 4 + 0][row] = v.x;
        xsT[k4 * 4 + 1][row] = v.y;
        xsT[k4 * 4 + 2][row] = v.z;
        xsT[k4 * 4 + 3][row] = v.w;
    }

    const int c0 = (t & 31) * 4;
    const int r0 = (t >> 5) * 4;
    float acc[4][4];
    #pragma unroll
    for (int i = 0; i < 4; ++i)
        #pragma unroll
        for (int j = 0; j < 4; ++j) acc[i][j] = 0.f;

    for (int kk = 0; kk < IN_F; kk += 32) {
        __syncthreads();
        // stage W chunk: k rows kk..kk+31, all 128 cols
        #pragma unroll
        for (int i = 0; i < 4; ++i) {
            int idx = t + i * 256;      // [0,1024)
            int wr = idx >> 5;          // 0..31
            int wc4 = idx & 31;
            *(float4*)&wch[wr][wc4 * 4] =
                *(const float4*)&W[(size_t)(kk + wr) * 128 + wc4 * 4];
        }
        __syncthreads();
        #pragma unroll 4
        for (int k = 0; k < 32; ++k) {
            float4 a = *(const float4*)&xsT[kk + k][r0];
            float4 w = *(const float4*)&wch[k][c0];
            acc[0][0] = fmaf(a.x, w.x, acc[0][0]);
            acc[0][1] = fmaf(a.x, w.y, acc[0][1]);
            acc[0][2] = fmaf(a.x, w.z, acc[0][2]);
            acc[0][3] = fmaf(a.x, w.w, acc[0][3]);
            acc[1][0] = fmaf(a.y, w.x, acc[1][0]);
            acc[1][1] = fmaf(a.y, w.y, acc[1][1]);
            acc[1][2] = fmaf(a.y, w.z, acc[1][2]);
            acc[1][3] = fmaf(a.y, w.w, acc[1][3]);
            acc[2][0] = fmaf(a.z, w.x, acc[2][0]);
            acc[2][1] = fmaf(a.z, w.y, acc[2][1]);
            acc[2][2] = fmaf(a.z, w.z, acc[2][2]);
            acc[2][3] = fmaf(a.z, w.w, acc[2][3]);
            acc[3][0] = fmaf(a.w, w.x, acc[3][0]);
            acc[3][1] = fmaf(a.w, w.y, acc[3][1]);
            acc[3][2] = fmaf(a.w, w.z, acc[3][2]);
            acc[3][3] = fmaf(a.w, w.w, acc[3][3]);
        }
    }

    #pragma unroll
    for (int i = 0; i < 4; ++i) {
        int r = row0 + r0 + i;
        if (r < N_NODES)
            *(float4*)&out[(size_t)r * 128 + c0] =
                make_float4(acc[i][0], acc[i][1], acc[i][2], acc[i][3]);
    }
}

__global__ __launch_bounds__(256) void gemm128_kernel(const float* __restrict__ X,
                                                      const float* __restrict__ W,
                                                      float* __restrict__ out) {
    gemm128_body(blockIdx.x, X, W, out);
}

// fat dispatch: odd blocks do count_deg, even blocks do layer-1 gemm.
// count_deg is atomic-latency bound (0.3% VALUBusy) so the gemm rides free.
__global__ __launch_bounds__(256) void fused_gemm1_count(
    const float* __restrict__ X, const float* __restrict__ W, float* __restrict__ out,
    const int* __restrict__ col, const float* __restrict__ ew,
    unsigned long long* __restrict__ packed) {
    int id = blockIdx.x;
    if (id & 1) {
        count_deg_body((id >> 1) * 256 + threadIdx.x, col, ew, packed);
    } else {
        int b = id >> 1;
        if (b < GEMM_BLOCKS) gemm128_body(b, X, W, out);
    }
}

// ---- two-level exclusive scan of counts -> row_ptr / cursor; dinv fused ----
__global__ void scan_reduce_dinv(const unsigned long long* __restrict__ packed,
                                 int* __restrict__ blockSums, float* __restrict__ dinv) {
    __shared__ int s[256];
    int i = blockIdx.x * 256 + threadIdx.x;
    unsigned long long p = (i < N_NODES) ? packed[i] : 0ull;
    if (i < N_NODES)
        dinv[i] = rsqrtf((float)(p & DEG_MASK) * (1.0f / DEG_SCALE) + 1.0f);
    s[threadIdx.x] = (int)(p >> 44);
    __syncthreads();
    for (int off = 128; off > 0; off >>= 1) {
        if (threadIdx.x < off) s[threadIdx.x] += s[threadIdx.x + off];
        __syncthreads();
    }
    if (threadIdx.x == 0) blockSums[blockIdx.x] = s[0];
}

__global__ void scan_offsets(const int* __restrict__ blockSums, int* __restrict__ offsets) {
    __shared__ int s[256];
    int t = threadIdx.x;
    int v = (t < SCAN_BLOCKS) ? blockSums[t] : 0;
    s[t] = v;
    __syncthreads();
    for (int off = 1; off < 256; off <<= 1) {
        int tmp = (t >= off) ? s[t - off] : 0;
        __syncthreads();
        s[t] += tmp;
        __syncthreads();
    }
    offsets[t] = s[t] - v;  // exclusive
}

__global__ void scan_final(const unsigned long long* __restrict__ packed,
                           const int* __restrict__ offsets,
                           int* __restrict__ row_ptr, int* __restrict__ cursor) {
    __shared__ int s[256];
    int t = threadIdx.x;
    int i = blockIdx.x * 256 + t;
    int v = (i < N_NODES) ? (int)(packed[i] >> 44) : 0;
    s[t] = v;
    __syncthreads();
    for (int off = 1; off < 256; off <<= 1) {
        int tmp = (t >= off) ? s[t - off] : 0;
        __syncthreads();
        s[t] += tmp;
        __syncthreads();
    }
    int incl = s[t] + offsets[blockIdx.x];
    if (i < N_NODES) {
        int excl = incl - v;
        row_ptr[i] = excl;
        cursor[i] = excl;
        if (i == N_NODES - 1) row_ptr[N_NODES] = incl;
    }
}

// scatter edges into CSR slots grouped by destination; store (src, norm) packed
__global__ void fill_kernel(const int* __restrict__ row, const int* __restrict__ col,
                            const float* __restrict__ ew, const float* __restrict__ dinv,
                            int* __restrict__ cursor, uint2* __restrict__ csr) {
    int e = blockIdx.x * blockDim.x + threadIdx.x;
    if (e >= N_EDGES) return;
    int r = row[e];
    int c = col[e];
    int pos = atomicAdd(&cursor[c], 1);
    float w = dinv[r] * ew[e] * dinv[c];
    csr[pos] = make_uint2((unsigned)r, __float_as_uint(w));
}

// h = X @ W, X:[N,128], W:[128,40].
__global__ void gemm40_kernel(const float* __restrict__ X, const float* __restrict__ W,
                              float* __restrict__ out) {
    __shared__ float xs[16 * IN_F];
    const int row0 = blockIdx.x * 16;
    for (int i = threadIdx.x; i < 16 * IN_F; i += 256)
        xs[i] = X[(size_t)row0 * IN_F + i];
    __syncthreads();
    for (int idx = threadIdx.x; idx < 16 * N_CLS; idx += 256) {
        int r = idx / N_CLS;
        int c = idx % N_CLS;
        float acc = 0.f;
        #pragma unroll 8
        for (int k = 0; k < IN_F; ++k)
            acc = fmaf(xs[r * IN_F + k], W[k * N_CLS + c], acc);
        out[(size_t)(row0 + r) * N_CLS + c] = acc;
    }
}

// Pull-aggregation + fused epilogue, F=128: one wave per node, lane = float2.
template <bool RELU>
__global__ void agg128_kernel(const int* __restrict__ row_ptr, const uint2* __restrict__ csr,
                              const float* __restrict__ h, const float* __restrict__ dinv,
                              const float* __restrict__ b, float* __restrict__ out) {
    int wave = threadIdx.x >> 6;
    int lane = threadIdx.x & 63;
    int node = blockIdx.x * 4 + wave;
    if (node >= N_NODES) return;
    int beg = row_ptr[node];
    int end = row_ptr[node + 1];
    int f = lane * 2;
    float2 acc = make_float2(0.f, 0.f);
    int k = beg;
    uint2 nxt;
    if (k < end) nxt = csr[k];
    while (k < end) {
        uint2 cur = nxt;
        ++k;
        if (k < end) nxt = csr[k];  // prefetch next edge record
        float w = __uint_as_float(cur.y);
        float2 hv = *(const float2*)&h[(size_t)cur.x * 128 + f];
        acc.x = fmaf(w, hv.x, acc.x);
        acc.y = fmaf(w, hv.y, acc.y);
    }
    float di = dinv[node];
    float di2 = di * di;
    float2 hs = *(const float2*)&h[(size_t)node * 128 + f];
    float2 bb = *(const float2*)&b[f];
    acc.x = fmaf(di2, hs.x, acc.x) + bb.x;
    acc.y = fmaf(di2, hs.y, acc.y) + bb.y;
    if (RELU) {
        acc.x = fmaxf(acc.x, 0.f);
        acc.y = fmaxf(acc.y, 0.f);
    }
    *(float2*)&out[(size_t)node * 128 + f] = acc;
}

// Pull-aggregation + epilogue, F=40: one wave per node, lanes 0..39 active.
__global__ void agg40_kernel(const int* __restrict__ row_ptr, const uint2* __restrict__ csr,
                             const float* __restrict__ h, const float* __restrict__ dinv,
                             const float* __restrict__ b, float* __restrict__ out) {
    int wave = threadIdx.x >> 6;
    int lane = threadIdx.x & 63;
    int node = blockIdx.x * 4 + wave;
    if (node >= N_NODES || lane >= N_CLS) return;
    int beg = row_ptr[node];
    int end = row_ptr[node + 1];
    float acc = 0.f;
    int k = beg;
    uint2 nxt;
    if (k < end) nxt = csr[k];
    while (k < end) {
        uint2 cur = nxt;
        ++k;
        if (k < end) nxt = csr[k];
        float w = __uint_as_float(cur.y);
        acc = fmaf(w, h[(size_t)cur.x * N_CLS + lane], acc);
    }
    float di = dinv[node];
    acc = fmaf(di * di, h[(size_t)node * N_CLS + lane], acc) + b[lane];
    out[(size_t)node * N_CLS + lane] = acc;
}

extern "C" void kernel_launch(void* const* d_in, const int* in_sizes, int n_in,
                              void* d_out, int out_size, void* d_ws, size_t ws_size,
                              hipStream_t stream) {
    const float* x  = (const float*)d_in[0];
    const float* ew = (const float*)d_in[1];
    const float* W1 = (const float*)d_in[2];
    const float* b1 = (const float*)d_in[3];
    const float* W2 = (const float*)d_in[4];
    const float* b2 = (const float*)d_in[5];
    const float* W3 = (const float*)d_in[6];
    const float* b3 = (const float*)d_in[7];
    const int*   ei = (const int*)d_in[8];
    const int* row = ei;
    const int* col = ei + N_EDGES;
    float* out = (float*)d_out;

    char* ws = (char*)d_ws;
    size_t off = 0;
    auto alloc = [&](size_t bytes) -> void* {
        void* p = (void*)(ws + off);
        off = (off + bytes + 255) & ~(size_t)255;
        return p;
    };
    unsigned long long* packed = (unsigned long long*)alloc((size_t)N_NODES * 8);
    float* dinv      = (float*)alloc((size_t)N_NODES * 4);
    int*   blockSums = (int*)alloc(256 * 4);
    int*   offsets   = (int*)alloc(256 * 4);
    int*   row_ptr   = (int*)alloc((size_t)(N_NODES + 1) * 4);
    int*   cursor    = (int*)alloc((size_t)N_NODES * 4);
    uint2* csr       = (uint2*)alloc((size_t)N_EDGES * 8);
    float* h         = (float*)alloc((size_t)N_NODES * HID * 4);
    float* hagg      = (float*)alloc((size_t)N_NODES * HID * 4);

    hipMemsetAsync(packed, 0, (size_t)N_NODES * 8, stream);

    // fat dispatch: layer-1 gemm (independent) overlapped with count_deg
    fused_gemm1_count<<<2 * CNT_BLOCKS, 256, 0, stream>>>(x, W1, h, col, ew, packed);

    scan_reduce_dinv<<<SCAN_BLOCKS, 256, 0, stream>>>(packed, blockSums, dinv);
    scan_offsets<<<1, 256, 0, stream>>>(blockSums, offsets);
    scan_final<<<SCAN_BLOCKS, 256, 0, stream>>>(packed, offsets, row_ptr, cursor);
    fill_kernel<<<cdiv(N_EDGES, 256), 256, 0, stream>>>(row, col, ew, dinv, cursor, csr);

    const int agg_blocks = cdiv(N_NODES, 4);  // 12500

    // --- layer 1 aggregation (gemm already done in fat dispatch) ---
    agg128_kernel<true><<<agg_blocks, 256, 0, stream>>>(row_ptr, csr, h, dinv, b1, hagg);

    // --- layer 2 ---
    gemm128_kernel<<<GEMM_BLOCKS, 256, 0, stream>>>(hagg, W2, h);
    agg128_kernel<true><<<agg_blocks, 256, 0, stream>>>(row_ptr, csr, h, dinv, b2, hagg);

    // --- layer 3 (output, no relu) ---
    gemm40_kernel<<<N_NODES / 16, 256, 0, stream>>>(hagg, W3, h);  // h reused as [N,40]
    agg40_kernel<<<agg_blocks, 256, 0, stream>>>(row_ptr, csr, h, dinv, b3, out);
}

// Round 4
// 432.428 us; speedup vs baseline: 2.5491x; 1.0505x over previous
//
#include <hip/hip_runtime.h>
#include <hip/hip_fp16.h>

#define N_NODES 50000
#define N_EDGES 800000
#define IN_F 128
#define HID 128
#define N_CLS 40
#define SCAN_BLOCKS 196        // ceil(50000/256)
#define GEMM_TILE_ROWS 32
#define GEMM_BLOCKS 1563       // ceil(50000/32)
#define CNT_BLOCKS 3125        // ceil(800000/256)
#define DEG_SCALE 2097152.0f   // 2^21 fixed-point for ew
#define DEG_MASK ((1ull << 44) - 1)

static inline int cdiv(int a, int b) { return (a + b - 1) / b; }

// ---- packed count+deg: one 64-bit atomic per edge ----
__device__ __forceinline__ void count_deg_body(int e, const int* __restrict__ col,
                                               const float* __restrict__ ew,
                                               unsigned long long* __restrict__ packed) {
    if (e < N_EDGES) {
        int c = col[e];
        unsigned long long v =
            (1ull << 44) | (unsigned long long)__float2uint_rn(ew[e] * DEG_SCALE);
        atomicAdd(&packed[c], v);
    }
}

// ---- gemm128 body: 32 rows x 128 cols per block, 4x4 register tile.
// Writes fp16 (the gather table for aggregation).
__device__ __forceinline__ void gemm128_body(int b, const float* __restrict__ X,
                                             const float* __restrict__ W,
                                             __half* __restrict__ out) {
    __shared__ float xsT[IN_F][GEMM_TILE_ROWS + 4];
    __shared__ float wch[32][128];
    const int t = threadIdx.x;
    const int row0 = b * GEMM_TILE_ROWS;

    #pragma unroll
    for (int i = 0; i < 4; ++i) {
        int idx = t + i * 256;
        int row = idx >> 5;
        int k4  = idx & 31;
        float4 v = make_float4(0.f, 0.f, 0.f, 0.f);
        if (row0 + row < N_NODES)
            v = *(const float4*)&X[(size_t)(row0 + row) * IN_F + k4 * 4];
        xsT[k4 * 4 + 0][row] = v.x;
        xsT[k4 * 4 + 1][row] = v.y;
        xsT[k4 * 4 + 2][row] = v.z;
        xsT[k4 * 4 + 3][row] = v.w;
    }

    const int c0 = (t & 31) * 4;
    const int r0 = (t >> 5) * 4;
    float acc[4][4];
    #pragma unroll
    for (int i = 0; i < 4; ++i)
        #pragma unroll
        for (int j = 0; j < 4; ++j) acc[i][j] = 0.f;

    for (int kk = 0; kk < IN_F; kk += 32) {
        __syncthreads();
        #pragma unroll
        for (int i = 0; i < 4; ++i) {
            int idx = t + i * 256;
            int wr = idx >> 5;
            int wc4 = idx & 31;
            *(float4*)&wch[wr][wc4 * 4] =
                *(const float4*)&W[(size_t)(kk + wr) * 128 + wc4 * 4];
        }
        __syncthreads();
        #pragma unroll 4
        for (int k = 0; k < 32; ++k) {
            float4 a = *(const float4*)&xsT[kk + k][r0];
            float4 w = *(const float4*)&wch[k][c0];
            acc[0][0] = fmaf(a.x, w.x, acc[0][0]);
            acc[0][1] = fmaf(a.x, w.y, acc[0][1]);
            acc[0][2] = fmaf(a.x, w.z, acc[0][2]);
            acc[0][3] = fmaf(a.x, w.w, acc[0][3]);
            acc[1][0] = fmaf(a.y, w.x, acc[1][0]);
            acc[1][1] = fmaf(a.y, w.y, acc[1][1]);
            acc[1][2] = fmaf(a.y, w.z, acc[1][2]);
            acc[1][3] = fmaf(a.y, w.w, acc[1][3]);
            acc[2][0] = fmaf(a.z, w.x, acc[2][0]);
            acc[2][1] = fmaf(a.z, w.y, acc[2][1]);
            acc[2][2] = fmaf(a.z, w.z, acc[2][2]);
            acc[2][3] = fmaf(a.z, w.w, acc[2][3]);
            acc[3][0] = fmaf(a.w, w.x, acc[3][0]);
            acc[3][1] = fmaf(a.w, w.y, acc[3][1]);
            acc[3][2] = fmaf(a.w, w.z, acc[3][2]);
            acc[3][3] = fmaf(a.w, w.w, acc[3][3]);
        }
    }

    #pragma unroll
    for (int i = 0; i < 4; ++i) {
        int r = row0 + r0 + i;
        if (r < N_NODES) {
            union { __half2 h2[2]; float2 f2; } u;
            u.h2[0] = __floats2half2_rn(acc[i][0], acc[i][1]);
            u.h2[1] = __floats2half2_rn(acc[i][2], acc[i][3]);
            *(float2*)&out[(size_t)r * 128 + c0] = u.f2;  // 8B aligned (c0 mult of 4)
        }
    }
}

__global__ __launch_bounds__(256) void gemm128_kernel(const float* __restrict__ X,
                                                      const float* __restrict__ W,
                                                      __half* __restrict__ out) {
    gemm128_body(blockIdx.x, X, W, out);
}

// fat dispatch: odd blocks do count_deg, even blocks do layer-1 gemm.
__global__ __launch_bounds__(256) void fused_gemm1_count(
    const float* __restrict__ X, const float* __restrict__ W, __half* __restrict__ out,
    const int* __restrict__ col, const float* __restrict__ ew,
    unsigned long long* __restrict__ packed) {
    int id = blockIdx.x;
    if (id & 1) {
        count_deg_body((id >> 1) * 256 + threadIdx.x, col, ew, packed);
    } else {
        int b = id >> 1;
        if (b < GEMM_BLOCKS) gemm128_body(b, X, W, out);
    }
}

// ---- two-level exclusive scan of counts -> row_ptr / cursor; dinv fused ----
__global__ void scan_reduce_dinv(const unsigned long long* __restrict__ packed,
                                 int* __restrict__ blockSums, float* __restrict__ dinv) {
    __shared__ int s[256];
    int i = blockIdx.x * 256 + threadIdx.x;
    unsigned long long p = (i < N_NODES) ? packed[i] : 0ull;
    if (i < N_NODES)
        dinv[i] = rsqrtf((float)(p & DEG_MASK) * (1.0f / DEG_SCALE) + 1.0f);
    s[threadIdx.x] = (int)(p >> 44);
    __syncthreads();
    for (int off = 128; off > 0; off >>= 1) {
        if (threadIdx.x < off) s[threadIdx.x] += s[threadIdx.x + off];
        __syncthreads();
    }
    if (threadIdx.x == 0) blockSums[blockIdx.x] = s[0];
}

__global__ void scan_offsets(const int* __restrict__ blockSums, int* __restrict__ offsets) {
    __shared__ int s[256];
    int t = threadIdx.x;
    int v = (t < SCAN_BLOCKS) ? blockSums[t] : 0;
    s[t] = v;
    __syncthreads();
    for (int off = 1; off < 256; off <<= 1) {
        int tmp = (t >= off) ? s[t - off] : 0;
        __syncthreads();
        s[t] += tmp;
        __syncthreads();
    }
    offsets[t] = s[t] - v;  // exclusive
}

__global__ void scan_final(const unsigned long long* __restrict__ packed,
                           const int* __restrict__ offsets,
                           int* __restrict__ row_ptr, int* __restrict__ cursor) {
    __shared__ int s[256];
    int t = threadIdx.x;
    int i = blockIdx.x * 256 + t;
    int v = (i < N_NODES) ? (int)(packed[i] >> 44) : 0;
    s[t] = v;
    __syncthreads();
    for (int off = 1; off < 256; off <<= 1) {
        int tmp = (t >= off) ? s[t - off] : 0;
        __syncthreads();
        s[t] += tmp;
        __syncthreads();
    }
    int incl = s[t] + offsets[blockIdx.x];
    if (i < N_NODES) {
        int excl = incl - v;
        row_ptr[i] = excl;
        cursor[i] = excl;
        if (i == N_NODES - 1) row_ptr[N_NODES] = incl;
    }
}

// scatter edges into CSR slots grouped by destination; store (src, norm) packed
__global__ void fill_kernel(const int* __restrict__ row, const int* __restrict__ col,
                            const float* __restrict__ ew, const float* __restrict__ dinv,
                            int* __restrict__ cursor, uint2* __restrict__ csr) {
    int e = blockIdx.x * blockDim.x + threadIdx.x;
    if (e >= N_EDGES) return;
    int r = row[e];
    int c = col[e];
    int pos = atomicAdd(&cursor[c], 1);
    float w = dinv[r] * ew[e] * dinv[c];
    csr[pos] = make_uint2((unsigned)r, __float_as_uint(w));
}

// h = X @ W, X:[N,128], W:[128,40], fp16 out.
__global__ void gemm40_kernel(const float* __restrict__ X, const float* __restrict__ W,
                              __half* __restrict__ out) {
    __shared__ float xs[16 * IN_F];
    const int row0 = blockIdx.x * 16;
    for (int i = threadIdx.x; i < 16 * IN_F; i += 256)
        xs[i] = X[(size_t)row0 * IN_F + i];
    __syncthreads();
    for (int idx = threadIdx.x; idx < 16 * N_CLS; idx += 256) {
        int r = idx / N_CLS;
        int c = idx % N_CLS;
        float acc = 0.f;
        #pragma unroll 8
        for (int k = 0; k < IN_F; ++k)
            acc = fmaf(xs[r * IN_F + k], W[k * N_CLS + c], acc);
        out[(size_t)(row0 + r) * N_CLS + c] = __float2half(acc);
    }
}

// Pull-aggregation + fused epilogue, F=128, fp16 gather table.
// One wave per node, lane covers 2 features; edge loop unrolled x2 w/ prefetch.
template <bool RELU>
__global__ void agg128_kernel(const int* __restrict__ row_ptr, const uint2* __restrict__ csr,
                              const __half* __restrict__ h, const float* __restrict__ dinv,
                              const float* __restrict__ b, float* __restrict__ out) {
    int wave = threadIdx.x >> 6;
    int lane = threadIdx.x & 63;
    int node = blockIdx.x * 4 + wave;
    if (node >= N_NODES) return;
    int beg = row_ptr[node];
    int end = row_ptr[node + 1];
    int f = lane * 2;
    float2 acc = make_float2(0.f, 0.f);

    int k = beg;
    uint2 a0, a1;
    if (k < end) a0 = csr[k];
    if (k + 1 < end) a1 = csr[k + 1];
    while (k < end) {
        uint2 c0 = a0, c1 = a1;
        bool two = (k + 1 < end);
        int kn = k + 2;
        if (kn < end) a0 = csr[kn];
        if (kn + 1 < end) a1 = csr[kn + 1];
        {
            float w = __uint_as_float(c0.y);
            float2 hf = __half22float2(*(const __half2*)&h[(size_t)c0.x * 128 + f]);
            acc.x = fmaf(w, hf.x, acc.x);
            acc.y = fmaf(w, hf.y, acc.y);
        }
        if (two) {
            float w = __uint_as_float(c1.y);
            float2 hf = __half22float2(*(const __half2*)&h[(size_t)c1.x * 128 + f]);
            acc.x = fmaf(w, hf.x, acc.x);
            acc.y = fmaf(w, hf.y, acc.y);
        }
        k = kn;
    }

    float di = dinv[node];
    float di2 = di * di;
    float2 hs = __half22float2(*(const __half2*)&h[(size_t)node * 128 + f]);
    float2 bb = *(const float2*)&b[f];
    acc.x = fmaf(di2, hs.x, acc.x) + bb.x;
    acc.y = fmaf(di2, hs.y, acc.y) + bb.y;
    if (RELU) {
        acc.x = fmaxf(acc.x, 0.f);
        acc.y = fmaxf(acc.y, 0.f);
    }
    *(float2*)&out[(size_t)node * 128 + f] = acc;
}

// Pull-aggregation + epilogue, F=40, fp16 gather table. Lanes 0..39 active.
__global__ void agg40_kernel(const int* __restrict__ row_ptr, const uint2* __restrict__ csr,
                             const __half* __restrict__ h, const float* __restrict__ dinv,
                             const float* __restrict__ b, float* __restrict__ out) {
    int wave = threadIdx.x >> 6;
    int lane = threadIdx.x & 63;
    int node = blockIdx.x * 4 + wave;
    if (node >= N_NODES || lane >= N_CLS) return;
    int beg = row_ptr[node];
    int end = row_ptr[node + 1];
    float acc = 0.f;
    int k = beg;
    uint2 a0, a1;
    if (k < end) a0 = csr[k];
    if (k + 1 < end) a1 = csr[k + 1];
    while (k < end) {
        uint2 c0 = a0, c1 = a1;
        bool two = (k + 1 < end);
        int kn = k + 2;
        if (kn < end) a0 = csr[kn];
        if (kn + 1 < end) a1 = csr[kn + 1];
        acc = fmaf(__uint_as_float(c0.y),
                   __half2float(h[(size_t)c0.x * N_CLS + lane]), acc);
        if (two)
            acc = fmaf(__uint_as_float(c1.y),
                       __half2float(h[(size_t)c1.x * N_CLS + lane]), acc);
        k = kn;
    }
    float di = dinv[node];
    acc = fmaf(di * di, __half2float(h[(size_t)node * N_CLS + lane]), acc) + b[lane];
    out[(size_t)node * N_CLS + lane] = acc;
}

extern "C" void kernel_launch(void* const* d_in, const int* in_sizes, int n_in,
                              void* d_out, int out_size, void* d_ws, size_t ws_size,
                              hipStream_t stream) {
    const float* x  = (const float*)d_in[0];
    const float* ew = (const float*)d_in[1];
    const float* W1 = (const float*)d_in[2];
    const float* b1 = (const float*)d_in[3];
    const float* W2 = (const float*)d_in[4];
    const float* b2 = (const float*)d_in[5];
    const float* W3 = (const float*)d_in[6];
    const float* b3 = (const float*)d_in[7];
    const int*   ei = (const int*)d_in[8];
    const int* row = ei;
    const int* col = ei + N_EDGES;
    float* out = (float*)d_out;

    char* ws = (char*)d_ws;
    size_t off = 0;
    auto alloc = [&](size_t bytes) -> void* {
        void* p = (void*)(ws + off);
        off = (off + bytes + 255) & ~(size_t)255;
        return p;
    };
    unsigned long long* packed = (unsigned long long*)alloc((size_t)N_NODES * 8);
    float*  dinv      = (float*)alloc((size_t)N_NODES * 4);
    int*    blockSums = (int*)alloc(256 * 4);
    int*    offsets   = (int*)alloc(256 * 4);
    int*    row_ptr   = (int*)alloc((size_t)(N_NODES + 1) * 4);
    int*    cursor    = (int*)alloc((size_t)N_NODES * 4);
    uint2*  csr       = (uint2*)alloc((size_t)N_EDGES * 8);
    __half* h16       = (__half*)alloc((size_t)N_NODES * HID * 2);
    float*  hagg      = (float*)alloc((size_t)N_NODES * HID * 4);

    hipMemsetAsync(packed, 0, (size_t)N_NODES * 8, stream);

    // fat dispatch: layer-1 gemm (independent) overlapped with count_deg
    fused_gemm1_count<<<2 * CNT_BLOCKS, 256, 0, stream>>>(x, W1, h16, col, ew, packed);

    scan_reduce_dinv<<<SCAN_BLOCKS, 256, 0, stream>>>(packed, blockSums, dinv);
    scan_offsets<<<1, 256, 0, stream>>>(blockSums, offsets);
    scan_final<<<SCAN_BLOCKS, 256, 0, stream>>>(packed, offsets, row_ptr, cursor);
    fill_kernel<<<cdiv(N_EDGES, 256), 256, 0, stream>>>(row, col, ew, dinv, cursor, csr);

    const int agg_blocks = cdiv(N_NODES, 4);  // 12500

    // --- layer 1 aggregation (gemm already done in fat dispatch) ---
    agg128_kernel<true><<<agg_blocks, 256, 0, stream>>>(row_ptr, csr, h16, dinv, b1, hagg);

    // --- layer 2 ---
    gemm128_kernel<<<GEMM_BLOCKS, 256, 0, stream>>>(hagg, W2, h16);
    agg128_kernel<true><<<agg_blocks, 256, 0, stream>>>(row_ptr, csr, h16, dinv, b2, hagg);

    // --- layer 3 (output, no relu) ---
    gemm40_kernel<<<N_NODES / 16, 256, 0, stream>>>(hagg, W3, h16);  // reused as [N,40] fp16
    agg40_kernel<<<agg_blocks, 256, 0, stream>>>(row_ptr, csr, h16, dinv, b3, out);
}

// Round 5
// 360.513 us; speedup vs baseline: 3.0575x; 1.1995x over previous
//
#include <hip/hip_runtime.h>
#include <hip/hip_fp16.h>

#define N_NODES 50000
#define N_EDGES 800000
#define IN_F 128
#define HID 128
#define N_CLS 40
#define SCAN_BLOCKS 196        // ceil(50000/256)
#define GEMM_TILE_ROWS 32
#define GEMM_BLOCKS 1563       // ceil(50000/32)
#define CNT_BLOCKS 3125        // ceil(800000/256)
#define DEG_SCALE 2097152.0f   // 2^21 fixed-point for ew
#define DEG_MASK ((1ull << 44) - 1)

static inline int cdiv(int a, int b) { return (a + b - 1) / b; }

// ---- packed count+deg: one 64-bit atomic per edge ----
__device__ __forceinline__ void count_deg_body(int e, const int* __restrict__ col,
                                               const float* __restrict__ ew,
                                               unsigned long long* __restrict__ packed) {
    if (e < N_EDGES) {
        int c = col[e];
        unsigned long long v =
            (1ull << 44) | (unsigned long long)__float2uint_rn(ew[e] * DEG_SCALE);
        atomicAdd(&packed[c], v);
    }
}

// ---- gemm128 body: 32 rows x 128 cols per block, 4x4 register tile, fp16 out ----
__device__ __forceinline__ void gemm128_body(int b, const float* __restrict__ X,
                                             const float* __restrict__ W,
                                             __half* __restrict__ out) {
    __shared__ float xsT[IN_F][GEMM_TILE_ROWS + 4];
    __shared__ float wch[32][128];
    const int t = threadIdx.x;
    const int row0 = b * GEMM_TILE_ROWS;

    #pragma unroll
    for (int i = 0; i < 4; ++i) {
        int idx = t + i * 256;
        int row = idx >> 5;
        int k4  = idx & 31;
        float4 v = make_float4(0.f, 0.f, 0.f, 0.f);
        if (row0 + row < N_NODES)
            v = *(const float4*)&X[(size_t)(row0 + row) * IN_F + k4 * 4];
        xsT[k4 * 4 + 0][row] = v.x;
        xsT[k4 * 4 + 1][row] = v.y;
        xsT[k4 * 4 + 2][row] = v.z;
        xsT[k4 * 4 + 3][row] = v.w;
    }

    const int c0 = (t & 31) * 4;
    const int r0 = (t >> 5) * 4;
    float acc[4][4];
    #pragma unroll
    for (int i = 0; i < 4; ++i)
        #pragma unroll
        for (int j = 0; j < 4; ++j) acc[i][j] = 0.f;

    for (int kk = 0; kk < IN_F; kk += 32) {
        __syncthreads();
        #pragma unroll
        for (int i = 0; i < 4; ++i) {
            int idx = t + i * 256;
            int wr = idx >> 5;
            int wc4 = idx & 31;
            *(float4*)&wch[wr][wc4 * 4] =
                *(const float4*)&W[(size_t)(kk + wr) * 128 + wc4 * 4];
        }
        __syncthreads();
        #pragma unroll 4
        for (int k = 0; k < 32; ++k) {
            float4 a = *(const float4*)&xsT[kk + k][r0];
            float4 w = *(const float4*)&wch[k][c0];
            acc[0][0] = fmaf(a.x, w.x, acc[0][0]);
            acc[0][1] = fmaf(a.x, w.y, acc[0][1]);
            acc[0][2] = fmaf(a.x, w.z, acc[0][2]);
            acc[0][3] = fmaf(a.x, w.w, acc[0][3]);
            acc[1][0] = fmaf(a.y, w.x, acc[1][0]);
            acc[1][1] = fmaf(a.y, w.y, acc[1][1]);
            acc[1][2] = fmaf(a.y, w.z, acc[1][2]);
            acc[1][3] = fmaf(a.y, w.w, acc[1][3]);
            acc[2][0] = fmaf(a.z, w.x, acc[2][0]);
            acc[2][1] = fmaf(a.z, w.y, acc[2][1]);
            acc[2][2] = fmaf(a.z, w.z, acc[2][2]);
            acc[2][3] = fmaf(a.z, w.w, acc[2][3]);
            acc[3][0] = fmaf(a.w, w.x, acc[3][0]);
            acc[3][1] = fmaf(a.w, w.y, acc[3][1]);
            acc[3][2] = fmaf(a.w, w.z, acc[3][2]);
            acc[3][3] = fmaf(a.w, w.w, acc[3][3]);
        }
    }

    #pragma unroll
    for (int i = 0; i < 4; ++i) {
        int r = row0 + r0 + i;
        if (r < N_NODES) {
            union { __half2 h2[2]; float2 f2; } u;
            u.h2[0] = __floats2half2_rn(acc[i][0], acc[i][1]);
            u.h2[1] = __floats2half2_rn(acc[i][2], acc[i][3]);
            *(float2*)&out[(size_t)r * 128 + c0] = u.f2;
        }
    }
}

__global__ __launch_bounds__(256) void gemm128_kernel(const float* __restrict__ X,
                                                      const float* __restrict__ W,
                                                      __half* __restrict__ out) {
    gemm128_body(blockIdx.x, X, W, out);
}

// fat dispatch: odd blocks do count_deg, even blocks do layer-1 gemm.
__global__ __launch_bounds__(256) void fused_gemm1_count(
    const float* __restrict__ X, const float* __restrict__ W, __half* __restrict__ out,
    const int* __restrict__ col, const float* __restrict__ ew,
    unsigned long long* __restrict__ packed) {
    int id = blockIdx.x;
    if (id & 1) {
        count_deg_body((id >> 1) * 256 + threadIdx.x, col, ew, packed);
    } else {
        int b = id >> 1;
        if (b < GEMM_BLOCKS) gemm128_body(b, X, W, out);
    }
}

// ---- two-level exclusive scan of counts -> row_ptr / cursor; dinv fused ----
__global__ void scan_reduce_dinv(const unsigned long long* __restrict__ packed,
                                 int* __restrict__ blockSums, float* __restrict__ dinv) {
    __shared__ int s[256];
    int i = blockIdx.x * 256 + threadIdx.x;
    unsigned long long p = (i < N_NODES) ? packed[i] : 0ull;
    if (i < N_NODES)
        dinv[i] = rsqrtf((float)(p & DEG_MASK) * (1.0f / DEG_SCALE) + 1.0f);
    s[threadIdx.x] = (int)(p >> 44);
    __syncthreads();
    for (int off = 128; off > 0; off >>= 1) {
        if (threadIdx.x < off) s[threadIdx.x] += s[threadIdx.x + off];
        __syncthreads();
    }
    if (threadIdx.x == 0) blockSums[blockIdx.x] = s[0];
}

__global__ void scan_offsets(const int* __restrict__ blockSums, int* __restrict__ offsets) {
    __shared__ int s[256];
    int t = threadIdx.x;
    int v = (t < SCAN_BLOCKS) ? blockSums[t] : 0;
    s[t] = v;
    __syncthreads();
    for (int off = 1; off < 256; off <<= 1) {
        int tmp = (t >= off) ? s[t - off] : 0;
        __syncthreads();
        s[t] += tmp;
        __syncthreads();
    }
    offsets[t] = s[t] - v;  // exclusive
}

__global__ void scan_final(const unsigned long long* __restrict__ packed,
                           const int* __restrict__ offsets,
                           int* __restrict__ row_ptr, int* __restrict__ cursor) {
    __shared__ int s[256];
    int t = threadIdx.x;
    int i = blockIdx.x * 256 + t;
    int v = (i < N_NODES) ? (int)(packed[i] >> 44) : 0;
    s[t] = v;
    __syncthreads();
    for (int off = 1; off < 256; off <<= 1) {
        int tmp = (t >= off) ? s[t - off] : 0;
        __syncthreads();
        s[t] += tmp;
        __syncthreads();
    }
    int incl = s[t] + offsets[blockIdx.x];
    if (i < N_NODES) {
        int excl = incl - v;
        row_ptr[i] = excl;
        cursor[i] = excl;
        if (i == N_NODES - 1) row_ptr[N_NODES] = incl;
    }
}

// scatter edges into CSR slots grouped by destination; store (src, norm) packed
__global__ void fill_kernel(const int* __restrict__ row, const int* __restrict__ col,
                            const float* __restrict__ ew, const float* __restrict__ dinv,
                            int* __restrict__ cursor, uint2* __restrict__ csr) {
    int e = blockIdx.x * blockDim.x + threadIdx.x;
    if (e >= N_EDGES) return;
    int r = row[e];
    int c = col[e];
    int pos = atomicAdd(&cursor[c], 1);
    float w = dinv[r] * ew[e] * dinv[c];
    csr[pos] = make_uint2((unsigned)r, __float_as_uint(w));
}

// h = X @ W, X:[N,128], W:[128,40], fp16 out.
__global__ void gemm40_kernel(const float* __restrict__ X, const float* __restrict__ W,
                              __half* __restrict__ out) {
    __shared__ float xs[16 * IN_F];
    const int row0 = blockIdx.x * 16;
    for (int i = threadIdx.x; i < 16 * IN_F; i += 256)
        xs[i] = X[(size_t)row0 * IN_F + i];
    __syncthreads();
    for (int idx = threadIdx.x; idx < 16 * N_CLS; idx += 256) {
        int r = idx / N_CLS;
        int c = idx % N_CLS;
        float acc = 0.f;
        #pragma unroll 8
        for (int k = 0; k < IN_F; ++k)
            acc = fmaf(xs[r * IN_F + k], W[k * N_CLS + c], acc);
        out[(size_t)(row0 + r) * N_CLS + c] = __float2half(acc);
    }
}

__device__ __forceinline__ void fma_h4(float w, uint2 g, float4& acc) {
    float2 lo = __half22float2(*(const __half2*)&g.x);
    float2 hi = __half22float2(*(const __half2*)&g.y);
    acc.x = fmaf(w, lo.x, acc.x);
    acc.y = fmaf(w, lo.y, acc.y);
    acc.z = fmaf(w, hi.x, acc.z);
    acc.w = fmaf(w, hi.y, acc.w);
}

// Pull-aggregation + fused epilogue, F=128, fp16 gather table.
// 2 nodes per wave (32 lanes x half4 each = 256B/row coalesced);
// edge loop unrolled x4 -> up to 8 outstanding gathers per wave.
template <bool RELU>
__global__ __launch_bounds__(256) void agg128_kernel(
    const int* __restrict__ row_ptr, const uint2* __restrict__ csr,
    const __half* __restrict__ h, const float* __restrict__ dinv,
    const float* __restrict__ b, float* __restrict__ out) {
    int wave = threadIdx.x >> 6;
    int lane = threadIdx.x & 63;
    int sub  = lane >> 5;       // which of the 2 nodes this half-wave owns
    int sl   = lane & 31;
    int node = blockIdx.x * 8 + wave * 2 + sub;
    if (node >= N_NODES) return;
    int beg = row_ptr[node];
    int end = row_ptr[node + 1];
    int f = sl * 4;             // 4 features per lane
    float4 acc = make_float4(0.f, 0.f, 0.f, 0.f);

    int k = beg;
    for (; k + 4 <= end; k += 4) {
        uint2 e0 = csr[k];
        uint2 e1 = csr[k + 1];
        uint2 e2 = csr[k + 2];
        uint2 e3 = csr[k + 3];
        uint2 g0 = *(const uint2*)&h[(size_t)e0.x * 128 + f];
        uint2 g1 = *(const uint2*)&h[(size_t)e1.x * 128 + f];
        uint2 g2 = *(const uint2*)&h[(size_t)e2.x * 128 + f];
        uint2 g3 = *(const uint2*)&h[(size_t)e3.x * 128 + f];
        fma_h4(__uint_as_float(e0.y), g0, acc);
        fma_h4(__uint_as_float(e1.y), g1, acc);
        fma_h4(__uint_as_float(e2.y), g2, acc);
        fma_h4(__uint_as_float(e3.y), g3, acc);
    }
    for (; k < end; ++k) {
        uint2 e = csr[k];
        uint2 g = *(const uint2*)&h[(size_t)e.x * 128 + f];
        fma_h4(__uint_as_float(e.y), g, acc);
    }

    float di = dinv[node];
    float di2 = di * di;
    uint2 gs = *(const uint2*)&h[(size_t)node * 128 + f];
    fma_h4(di2, gs, acc);
    float4 bb = *(const float4*)&b[f];
    acc.x += bb.x; acc.y += bb.y; acc.z += bb.z; acc.w += bb.w;
    if (RELU) {
        acc.x = fmaxf(acc.x, 0.f);
        acc.y = fmaxf(acc.y, 0.f);
        acc.z = fmaxf(acc.z, 0.f);
        acc.w = fmaxf(acc.w, 0.f);
    }
    *(float4*)&out[(size_t)node * 128 + f] = acc;
}

// Pull-aggregation + epilogue, F=40, fp16 gather table. Lanes 0..39, unroll x4.
__global__ __launch_bounds__(256) void agg40_kernel(
    const int* __restrict__ row_ptr, const uint2* __restrict__ csr,
    const __half* __restrict__ h, const float* __restrict__ dinv,
    const float* __restrict__ b, float* __restrict__ out) {
    int wave = threadIdx.x >> 6;
    int lane = threadIdx.x & 63;
    int node = blockIdx.x * 4 + wave;
    if (node >= N_NODES || lane >= N_CLS) return;
    int beg = row_ptr[node];
    int end = row_ptr[node + 1];
    float acc = 0.f;
    int k = beg;
    for (; k + 4 <= end; k += 4) {
        uint2 e0 = csr[k];
        uint2 e1 = csr[k + 1];
        uint2 e2 = csr[k + 2];
        uint2 e3 = csr[k + 3];
        float g0 = __half2float(h[(size_t)e0.x * N_CLS + lane]);
        float g1 = __half2float(h[(size_t)e1.x * N_CLS + lane]);
        float g2 = __half2float(h[(size_t)e2.x * N_CLS + lane]);
        float g3 = __half2float(h[(size_t)e3.x * N_CLS + lane]);
        acc = fmaf(__uint_as_float(e0.y), g0, acc);
        acc = fmaf(__uint_as_float(e1.y), g1, acc);
        acc = fmaf(__uint_as_float(e2.y), g2, acc);
        acc = fmaf(__uint_as_float(e3.y), g3, acc);
    }
    for (; k < end; ++k) {
        uint2 e = csr[k];
        acc = fmaf(__uint_as_float(e.y),
                   __half2float(h[(size_t)e.x * N_CLS + lane]), acc);
    }
    float di = dinv[node];
    acc = fmaf(di * di, __half2float(h[(size_t)node * N_CLS + lane]), acc) + b[lane];
    out[(size_t)node * N_CLS + lane] = acc;
}

extern "C" void kernel_launch(void* const* d_in, const int* in_sizes, int n_in,
                              void* d_out, int out_size, void* d_ws, size_t ws_size,
                              hipStream_t stream) {
    const float* x  = (const float*)d_in[0];
    const float* ew = (const float*)d_in[1];
    const float* W1 = (const float*)d_in[2];
    const float* b1 = (const float*)d_in[3];
    const float* W2 = (const float*)d_in[4];
    const float* b2 = (const float*)d_in[5];
    const float* W3 = (const float*)d_in[6];
    const float* b3 = (const float*)d_in[7];
    const int*   ei = (const int*)d_in[8];
    const int* row = ei;
    const int* col = ei + N_EDGES;
    float* out = (float*)d_out;

    char* ws = (char*)d_ws;
    size_t off = 0;
    auto alloc = [&](size_t bytes) -> void* {
        void* p = (void*)(ws + off);
        off = (off + bytes + 255) & ~(size_t)255;
        return p;
    };
    unsigned long long* packed = (unsigned long long*)alloc((size_t)N_NODES * 8);
    float*  dinv      = (float*)alloc((size_t)N_NODES * 4);
    int*    blockSums = (int*)alloc(256 * 4);
    int*    offsets   = (int*)alloc(256 * 4);
    int*    row_ptr   = (int*)alloc((size_t)(N_NODES + 1) * 4);
    int*    cursor    = (int*)alloc((size_t)N_NODES * 4);
    uint2*  csr       = (uint2*)alloc((size_t)N_EDGES * 8);
    __half* h16       = (__half*)alloc((size_t)N_NODES * HID * 2);
    float*  hagg      = (float*)alloc((size_t)N_NODES * HID * 4);

    hipMemsetAsync(packed, 0, (size_t)N_NODES * 8, stream);

    // fat dispatch: layer-1 gemm (independent) overlapped with count_deg
    fused_gemm1_count<<<2 * CNT_BLOCKS, 256, 0, stream>>>(x, W1, h16, col, ew, packed);

    scan_reduce_dinv<<<SCAN_BLOCKS, 256, 0, stream>>>(packed, blockSums, dinv);
    scan_offsets<<<1, 256, 0, stream>>>(blockSums, offsets);
    scan_final<<<SCAN_BLOCKS, 256, 0, stream>>>(packed, offsets, row_ptr, cursor);
    fill_kernel<<<cdiv(N_EDGES, 256), 256, 0, stream>>>(row, col, ew, dinv, cursor, csr);

    const int agg128_blocks = cdiv(N_NODES, 8);  // 6250 (8 nodes/block)
    const int agg40_blocks  = cdiv(N_NODES, 4);  // 12500

    // --- layer 1 aggregation (gemm already done in fat dispatch) ---
    agg128_kernel<true><<<agg128_blocks, 256, 0, stream>>>(row_ptr, csr, h16, dinv, b1, hagg);

    // --- layer 2 ---
    gemm128_kernel<<<GEMM_BLOCKS, 256, 0, stream>>>(hagg, W2, h16);
    agg128_kernel<true><<<agg128_blocks, 256, 0, stream>>>(row_ptr, csr, h16, dinv, b2, hagg);

    // --- layer 3 (output, no relu) ---
    gemm40_kernel<<<N_NODES / 16, 256, 0, stream>>>(hagg, W3, h16);  // reused as [N,40] fp16
    agg40_kernel<<<agg40_blocks, 256, 0, stream>>>(row_ptr, csr, h16, dinv, b3, out);
}